// Round 4
// baseline (729.651 us; speedup 1.0000x reference)
//
#include <hip/hip_runtime.h>
#include <cstdint>
#include <cstddef>

#define B_  256
#define T_  128
#define NS_ 12
#define NC_ 4
#define M_  6

constexpr float MU_F      = 0.1f;
constexpr float REG_FAC_F = (float)(1.6 * 1.6 - 1.0);   // 1.56 -> f32

// ---- staging buffer layout (float offsets) ----
#define OF_FX   0
#define OF_FU   144
#define OF_FXX  192
#define OF_FXU  1920
#define OF_FUU  2496
#define OF_QXX  2688
#define OF_QXU  2832
#define OF_QUU  2880
#define OF_QX   2896
#define OF_QU   2908
#define OF_CX   2912
#define OF_CU   2984
#define OF_C    3008
#define OF_S    3014
#define STG_N   3020

// ---- output layout (float offsets into d_out) ----
#define O_KU    0
#define O_KUBIG 131072
#define O_KS    1703936
#define O_KSBIG 1900544
#define O_DV    4259840
#define O_OPT   4260352
#define O_VX    4260353
#define O_VXX   4263425

// Single-wave blocks: no s_barrier anywhere. Phase fence = drain LDS ops.
// "memory" clobber orders all memory ops across the fence; no sched_barrier so
// the compiler may still overlap register-only compute across phases.
__device__ __forceinline__ void wsync_lds() {
    asm volatile("s_waitcnt lgkmcnt(0)" ::: "memory");
}
__device__ __forceinline__ void wsync_all() {
    asm volatile("s_waitcnt vmcnt(0) lgkmcnt(0)" ::: "memory");
}

__device__ __forceinline__ void gl_lds16(const float* g, float* l) {
    __builtin_amdgcn_global_load_lds((const __attribute__((address_space(1))) void*)g,
                                     (__attribute__((address_space(3))) void*)l, 16, 0, 0);
}
__device__ __forceinline__ void gl_lds4(const float* g, float* l) {
    __builtin_amdgcn_global_load_lds((const __attribute__((address_space(1))) void*)g,
                                     (__attribute__((address_space(3))) void*)l, 4, 0, 0);
}
__device__ __forceinline__ float4 ld4(const float* p)  { return *reinterpret_cast<const float4*>(p); }
__device__ __forceinline__ void   st4(float* p, float4 v) { *reinterpret_cast<float4*>(p) = v; }

__global__ __launch_bounds__(64) void ddp_backward(
    const float* __restrict__ qx,  const float* __restrict__ qu,
    const float* __restrict__ qxx, const float* __restrict__ qxu,
    const float* __restrict__ quu, const float* __restrict__ fx,
    const float* __restrict__ fu,  const float* __restrict__ fxx,
    const float* __restrict__ fxu, const float* __restrict__ fuu,
    const float* __restrict__ cx,  const float* __restrict__ cu,
    const float* __restrict__ c_,  const float* __restrict__ s_,
    const float* __restrict__ px,  const float* __restrict__ pxx,
    float* __restrict__ out, float* __restrict__ ws)
{
    const int l = threadIdx.x;     // lane 0..63 (one wave per block/batch)
    const int b = blockIdx.x;

    __shared__ alignas(16) float stg[2][STG_N];
    __shared__ alignas(16) float sVxe[192];     // carry padded [12][16]: cols 0-11 Vxx, col 12 Vx
    __shared__ alignas(16) float sG[192];       // [p][k] stride 12: rows 0-11 fxV, 12-15 fuV
    __shared__ alignas(16) float sOUT[192];     // [i][q] stride 16: q<12 Qxx2, q>=12 tempQux[a][i]
    __shared__ alignas(16) float sQuuR[16], sQuu2[16], sM4[16];
    __shared__ alignas(16) float sQP[16];       // Qx2 (0-11) | Qu final (12-15)
    __shared__ alignas(16) float sKu[48];       // [a][i] stride 12
    __shared__ alignas(16) float sku[4];
    __shared__ alignas(16) float sR[8], sCINV[8], sSC[8];
    __shared__ float sAcc[4];

    const float* srcs[14] = {qx, qu, qxx, qxu, quu, fx, fu, fxx, fxu, fuu, cx, cu, c_, s_};

    // ---- per-lane role constants ----
    const int p   = l & 15, cq = l >> 4;
    const bool cq3 = (cq == 3);
    const int u1_x  = (p < 12) ? (OF_FX + p) : (OF_FU + p - 12);
    const int u1_xs = (p < 12) ? 12 : 4;
    const int u1_q0 = (p < 12) ? (OF_QX + p) : (OF_QU + p - 12);
    const int u1_w  = (p < 12) ? (OF_CX + p) : (OF_CU + p - 12);
    const int u1_ws = (p < 12) ? 12 : 4;
    const int pr = l >> 2, q4 = l & 3;
    const bool q43 = (q4 == 3);
    const int u2_q0 = (pr < 12) ? (q43 ? (OF_QXU + pr * 4) : (OF_QXX + pr * 12 + q4 * 4))
                                : (OF_QUU + (pr - 12) * 4);
    const int u2_x  = q43 ? OF_FU : (OF_FX + q4 * 4);
    const int u2_xs = q43 ? 4 : 12;
    const int u2_t  = (pr < 12) ? (q43 ? (OF_FXU + pr * 4) : (OF_FXX + pr * 12 + q4 * 4))
                                : (OF_FUU + (pr - 12) * 4);
    const int u2_ts = (pr < 12) ? (q43 ? 48 : 144) : 16;
    const int u2_w  = q43 ? OF_CU : (OF_CX + q4 * 4);
    const int u2_ws = q43 ? 4 : 12;
    const int i5 = l / 3, jq5 = l % 3;

    auto prefetch = [&](float* dst, int tt) {
        const uint32_t bt2 = (uint32_t)b * T_ + (uint32_t)tt;
        constexpr int ch_arr[22]  = {5,6,7,7,7,7,7,7,7,8,8,8,9,2,3,4,0,1,10,11,12,13};
        constexpr int ch_goff[22] = {0,0,0,256,512,768,1024,1280,1536,0,256,512,0,0,0,0,0,0,0,0,0,0};
        constexpr int ch_loff[22] = {OF_FX, OF_FU,
                                     OF_FXX, OF_FXX+256, OF_FXX+512, OF_FXX+768,
                                     OF_FXX+1024, OF_FXX+1280, OF_FXX+1536,
                                     OF_FXU, OF_FXU+256, OF_FXU+512,
                                     OF_FUU, OF_QXX, OF_QXU, OF_QUU, OF_QX, OF_QU,
                                     OF_CX, OF_CU, OF_C, OF_S};
        constexpr int ch_nb[22]   = {576,192,1024,1024,1024,1024,1024,1024,768,
                                     1024,1024,256,768,576,192,64,48,16,288,96,24,24};
        constexpr int sl[14]      = {12,4,144,48,16,144,48,1728,576,192,72,24,6,6};
        #pragma unroll
        for (int ci = 0; ci < 22; ++ci) {
            const uint32_t off = bt2 * (uint32_t)sl[ch_arr[ci]] + (uint32_t)ch_goff[ci];
            const float* g = srcs[ch_arr[ci]] + (size_t)off;
            float* dl = dst + ch_loff[ci];
            if ((ch_nb[ci] & 15) == 0) {
                if (l * 16 < ch_nb[ci]) gl_lds16(g + l * 4, dl);
            } else {
                if (l * 4  < ch_nb[ci]) gl_lds4 (g + l,     dl);
            }
        }
    };

    // ---------- prologue ----------
    #pragma unroll
    for (int idx = l; idx < 192; idx += 64) {
        const int r = idx >> 4, ci = idx & 15;
        float v = 0.f;
        if (ci < 12)       v = pxx[(size_t)b * 144 + r * 12 + ci];
        else if (ci == 12) v = px[(size_t)b * 12 + r];
        sVxe[idx] = v;
    }
    prefetch(stg[0], T_ - 1);
    wsync_all();

    float dv0 = 0.f, dv1 = 0.f, qerr = 0.f, merr = 0.f;
    int cur = 0;
    for (int t = T_ - 1; t >= 0; --t) {
        const float* S = stg[cur];
        const uint32_t bt = (uint32_t)b * T_ + (uint32_t)t;

        // ================= U1 load issue (+ U2 staging preloads) =================
        // U1's own operands
        float fcol[12];
        float4 vrow[12];
        #pragma unroll
        for (int m = 0; m < 12; ++m) fcol[m] = S[u1_x + m * u1_xs];
        #pragma unroll
        for (int m = 0; m < 12; ++m) vrow[m] = ld4(sVxe + m * 16 + cq * 4);
        // C|S block (12 floats, aligned): c[0..5]=q0.x..q1.y, s[0..5]=q1.z..q2.w
        const float4 csq0 = ld4(S + OF_C);
        const float4 csq1 = ld4(S + OF_C + 4);
        const float4 csq2 = ld4(S + OF_C + 8);
        // U2 preloads (stable staging data; latency hides under U1 compute)
        float4 u2f[12];
        #pragma unroll
        for (int k = 0; k < 12; ++k) u2f[k] = ld4(S + u2_x + k * u2_xs);
        const float4 u2q0 = ld4(S + u2_q0);
        float4 u2tv[12];
        #pragma unroll
        for (int s2 = 0; s2 < 12; ++s2) u2tv[s2] = ld4(S + u2_t + s2 * u2_ts);

        // ================= prefetch issue (hides under the loads above) =================
        if (t > 0) prefetch(stg[cur ^ 1], t - 1);

        // ================= U1 compute: G = [fx|fu]^T [Vxx|Vx], Qx/Qu chain, r/cinv/sc =================
        {
            if (cq3 && p < 6) {
                const float cc = S[OF_C + p], sv = S[OF_S + p];
                sR[p]    = sv * cc + MU_F;
                sCINV[p] = 1.0f / cc;
                sSC[p]   = sv / cc;
            }
            float accx = 0.f, accy = 0.f, accz = 0.f, accw = 0.f;
            if (cq3) {
                float a0 = S[u1_q0];
                #pragma unroll
                for (int k = 0; k < 6; ++k) a0 += S[u1_w + k * u1_ws] * S[OF_S + k];
                accx = a0;
            }
            #pragma unroll
            for (int m = 0; m < 12; ++m) {
                const float f = fcol[m];
                accx += f * vrow[m].x; accy += f * vrow[m].y;
                accz += f * vrow[m].z; accw += f * vrow[m].w;
            }
            if (!cq3) {
                st4(sG + p * 12 + cq * 4, make_float4(accx, accy, accz, accw));
            } else {
                // redundant per-lane IEEE cinv/r (bitwise == the sCINV/sR stores above)
                const float cv[6] = {csq0.x, csq0.y, csq0.z, csq0.w, csq1.x, csq1.y};
                const float sv[6] = {csq1.z, csq1.w, csq2.x, csq2.y, csq2.z, csq2.w};
                float rck[6], rrk[6];
                #pragma unroll
                for (int k = 0; k < 6; ++k) { rck[k] = 1.0f / cv[k]; rrk[k] = sv[k] * cv[k] + MU_F; }
                #pragma unroll
                for (int k = 0; k < 6; ++k) accx -= S[u1_w + k * u1_ws] * rck[k] * rrk[k];
                sQP[p] = accx;
            }
        }
        wsync_lds();

        // ================= U2: combined 16x16 {Qxx2 | tempQux | QuuR} + B2 fold =================
        {
            float vx[12];
            #pragma unroll
            for (int m = 0; m < 12; ++m) vx[m] = sVxe[m * 16 + 12];
            float rsc[6];
            #pragma unroll
            for (int k = 0; k < 6; ++k) rsc[k] = sSC[k];

            const float4 g0 = ld4(sG + pr * 12);
            const float4 g1 = ld4(sG + pr * 12 + 4);
            const float4 g2 = ld4(sG + pr * 12 + 8);
            const float gk[12] = {g0.x,g0.y,g0.z,g0.w, g1.x,g1.y,g1.z,g1.w, g2.x,g2.y,g2.z,g2.w};

            float4 acc = u2q0;
            #pragma unroll
            for (int k = 0; k < 12; ++k) {
                const float4 f = u2f[k];
                acc.x += gk[k]*f.x; acc.y += gk[k]*f.y; acc.z += gk[k]*f.z; acc.w += gk[k]*f.w;
            }
            #pragma unroll
            for (int s2 = 0; s2 < 12; ++s2) {
                const float4 tv = u2tv[s2];
                acc.x += vx[s2]*tv.x; acc.y += vx[s2]*tv.y; acc.z += vx[s2]*tv.z; acc.w += vx[s2]*tv.w;
            }
            if (pr < 12) {
                #pragma unroll
                for (int k = 0; k < 6; ++k) {
                    const float t2 = rsc[k] * S[OF_CX + k * 12 + pr];
                    const float4 cv = ld4(S + u2_w + k * u2_ws);
                    acc.x -= t2*cv.x; acc.y -= t2*cv.y; acc.z -= t2*cv.z; acc.w -= t2*cv.w;
                }
                st4(sOUT + pr * 16 + q4 * 4, acc);
            } else if (q43) {
                st4(sQuuR + (pr - 12) * 4, acc);
            }
            wsync_lds();   // uniform: sQuuR (and sOUT) visible
            if (pr >= 12 && q43) {      // B2 fold: symmetrize + cuSCcu + reg
                const int a = pr - 12;
                const float accq[4] = {acc.x, acc.y, acc.z, acc.w};
                float q2v[4];
                #pragma unroll
                for (int bb = 0; bb < 4; ++bb) {
                    const float q = 0.5f * (accq[bb] + sQuuR[bb * 4 + a]);
                    float cs2 = 0.f;
                    #pragma unroll
                    for (int k = 0; k < 6; ++k)
                        cs2 += rsc[k] * S[OF_CU + k*4 + a] * S[OF_CU + k*4 + bb];
                    q2v[bb] = q - cs2;
                }
                const float4 quuq = ld4(S + OF_QUU + a * 4);
                st4(sQuu2 + a * 4, make_float4(q2v[0], q2v[1], q2v[2], q2v[3]));
                st4(sM4   + a * 4, make_float4(q2v[0] + quuq.x * REG_FAC_F,
                                               q2v[1] + quuq.y * REG_FAC_F,
                                               q2v[2] + quuq.z * REG_FAC_F,
                                               q2v[3] + quuq.w * REG_FAC_F));
            }
        }
        wsync_lds();

        // ================= LU: 4x4 solve (13 RHS) + dV folds + err trackers =================
        if (l < 13) {
            float a00=sM4[0],  a01=sM4[1],  a02=sM4[2],  a03=sM4[3];
            float a10=sM4[4],  a11=sM4[5],  a12=sM4[6],  a13=sM4[7];
            float a20=sM4[8],  a21=sM4[9],  a22=sM4[10], a23=sM4[11];
            float a30=sM4[12], a31=sM4[13], a32=sM4[14], a33=sM4[15];
            const float i0 = 1.0f / a00;
            const float l10 = a10*i0, l20 = a20*i0, l30 = a30*i0;
            a11 -= l10*a01; a12 -= l10*a02; a13 -= l10*a03;
            a21 -= l20*a01; a22 -= l20*a02; a23 -= l20*a03;
            a31 -= l30*a01; a32 -= l30*a02; a33 -= l30*a03;
            const float i1 = 1.0f / a11;
            const float l21 = a21*i1, l31 = a31*i1;
            a22 -= l21*a12; a23 -= l21*a13;
            a32 -= l31*a12; a33 -= l31*a13;
            const float i2 = 1.0f / a22;
            const float l32 = a32*i2;
            a33 -= l32*a23;

            float r0, r1, r2, r3;
            if (l == 0) { const float4 q = ld4(sQP + 12);             r0=q.x; r1=q.y; r2=q.z; r3=q.w; }
            else        { const float4 q = ld4(sOUT + (l-1)*16 + 12); r0=q.x; r1=q.y; r2=q.z; r3=q.w; }

            const float y0 = r0;
            const float y1 = r1 - l10*y0;
            const float y2 = r2 - l20*y0 - l21*y1;
            const float y3 = r3 - l30*y0 - l31*y1 - l32*y2;
            float x3 = y3 / a33;
            float x2 = (y2 - a23*x3) * i2;
            float x1 = (y1 - a12*x2 - a13*x3) * i1;
            float x0 = (y0 - a01*x1 - a02*x2 - a03*x3) * i0;
            x0 = -x0; x1 = -x1; x2 = -x2; x3 = -x3;

            if (l == 0) {
                sku[0]=x0; sku[1]=x1; sku[2]=x2; sku[3]=x3;
                st4(out + O_KU + (size_t)bt * 4, make_float4(x0, x1, x2, x3));
                const float kux[4] = {x0, x1, x2, x3};
                float d0 = 0.f;
                #pragma unroll
                for (int a = 0; a < 4; ++a) d0 += kux[a] * sQP[12 + a];
                dv0 += d0;
                float d1 = 0.f;
                #pragma unroll
                for (int a = 0; a < 4; ++a)
                    #pragma unroll
                    for (int b2 = 0; b2 < 4; ++b2) d1 += kux[a] * sQuu2[a*4 + b2] * kux[b2];
                dv1 += 0.5f * d1;
            } else {
                const int i = l - 1;
                sKu[i]=x0; sKu[12+i]=x1; sKu[24+i]=x2; sKu[36+i]=x3;
                float* Kg = out + O_KUBIG + (size_t)bt * 48;
                Kg[i]=x0; Kg[12+i]=x1; Kg[24+i]=x2; Kg[36+i]=x3;
            }
        } else if (l == 20) {
            float m = 0.f;
            #pragma unroll
            for (int a = 0; a < 4; ++a) m = fmaxf(m, fabsf(sQP[12 + a]));
            qerr = fmaxf(qerr, m);
        } else if (l == 21) {
            float m = 0.f;
            #pragma unroll
            for (int k = 0; k < 6; ++k) m = fmaxf(m, fabsf(sR[k]));
            merr = fmaxf(merr, m);
        }
        wsync_lds();

        // ================= TAIL: Ks+ks first (stores issue early), then Vxx | Vx =================
        if (l < 18) {
            const int k = i5, iq = jq5;
            const float4 cxv = ld4(S + OF_CX + k*12 + iq*4);
            float a0 = cxv.x, a1 = cxv.y, a2 = cxv.z, a3v = cxv.w;
            #pragma unroll
            for (int a = 0; a < 4; ++a) {
                const float  cua = S[OF_CU + k*4 + a];
                const float4 kv  = ld4(sKu + a*12 + iq*4);
                a0 += cua*kv.x; a1 += cua*kv.y; a2 += cua*kv.z; a3v += cua*kv.w;
            }
            const float ns = -sSC[k];
            st4(out + O_KSBIG + (size_t)bt * 72 + k*12 + iq*4,
                make_float4(ns*a0, ns*a1, ns*a2, ns*a3v));
            if (iq == 0) {
                float cuku = 0.f;
                #pragma unroll
                for (int a = 0; a < 4; ++a) cuku += S[OF_CU + k*4 + a] * sku[a];
                out[O_KS + (size_t)bt * 6 + k] = -sCINV[k] * (sR[k] + S[OF_S + k] * cuku);
            }
        }
        if (l < 36) {
            const int i = i5, jq = jq5;
            const float4 v14  = ld4(sOUT + i*16 + jq*4);
            const float4 tqi4 = ld4(sOUT + i*16 + 12);
            const float tqi[4] = {tqi4.x, tqi4.y, tqi4.z, tqi4.w};
            float kuj[4][4], kui[4];
            #pragma unroll
            for (int a = 0; a < 4; ++a) {
                const float4 kv = ld4(sKu + a*12 + jq*4);
                kuj[a][0]=kv.x; kuj[a][1]=kv.y; kuj[a][2]=kv.z; kuj[a][3]=kv.w;
                kui[a] = sKu[a*12 + i];
            }
            float4 q2r[4];
            #pragma unroll
            for (int bb = 0; bb < 4; ++bb) q2r[bb] = ld4(sQuu2 + bb*4);
            float kqi[4] = {0.f, 0.f, 0.f, 0.f};
            #pragma unroll
            for (int bb = 0; bb < 4; ++bb) {
                kqi[0] += kui[bb]*q2r[bb].x; kqi[1] += kui[bb]*q2r[bb].y;
                kqi[2] += kui[bb]*q2r[bb].z; kqi[3] += kui[bb]*q2r[bb].w;
            }
            float kqj[4][4];
            #pragma unroll
            for (int r = 0; r < 4; ++r) { kqj[r][0]=0.f; kqj[r][1]=0.f; kqj[r][2]=0.f; kqj[r][3]=0.f; }
            #pragma unroll
            for (int bb = 0; bb < 4; ++bb) {
                #pragma unroll
                for (int r = 0; r < 4; ++r) {
                    kqj[r][0] += kuj[bb][r]*q2r[bb].x; kqj[r][1] += kuj[bb][r]*q2r[bb].y;
                    kqj[r][2] += kuj[bb][r]*q2r[bb].z; kqj[r][3] += kuj[bb][r]*q2r[bb].w;
                }
            }
            const float v1a[4] = {v14.x, v14.y, v14.z, v14.w};
            float v2[4], tqj[4][4];
            #pragma unroll
            for (int r = 0; r < 4; ++r) {
                const int j = jq*4 + r;
                v2[r] = sOUT[j*16 + i];
                const float4 tq = ld4(sOUT + j*16 + 12);
                tqj[r][0]=tq.x; tqj[r][1]=tq.y; tqj[r][2]=tq.z; tqj[r][3]=tq.w;
            }
            float res[4];
            #pragma unroll
            for (int r = 0; r < 4; ++r) {
                float qk = 0.f, kk1 = 0.f, kk2 = 0.f;
                #pragma unroll
                for (int a = 0; a < 4; ++a) {
                    qk  += tqi[a]*kuj[a][r] + tqj[r][a]*kui[a];
                    kk1 += kqi[a]*kuj[a][r];
                    kk2 += kqj[r][a]*kui[a];
                }
                res[r] = 0.5f*(v1a[r] + v2[r]) + qk + 0.5f*(kk1 + kk2);
            }
            st4(sVxe + i*16 + jq*4, make_float4(res[0], res[1], res[2], res[3]));
        } else if (l < 48) {
            const int i = l - 36;
            float kub[4];
            #pragma unroll
            for (int bb = 0; bb < 4; ++bb) kub[bb] = sKu[bb*12 + i];
            float4 q2r[4];
            #pragma unroll
            for (int bb = 0; bb < 4; ++bb) q2r[bb] = ld4(sQuu2 + bb*4);
            float ktq[4] = {0.f, 0.f, 0.f, 0.f};
            #pragma unroll
            for (int bb = 0; bb < 4; ++bb) {
                ktq[0] += kub[bb]*q2r[bb].x; ktq[1] += kub[bb]*q2r[bb].y;
                ktq[2] += kub[bb]*q2r[bb].z; ktq[3] += kub[bb]*q2r[bb].w;
            }
            float acc = sQP[i];
            #pragma unroll
            for (int a = 0; a < 4; ++a)
                acc += kub[a]*sQP[12+a] + ktq[a]*sku[a] + sOUT[i*16+12+a]*sku[a];
            st4(sVxe + i*16 + 12, make_float4(acc, 0.f, 0.f, 0.f));
        }
        wsync_all();   // carry written + prefetch for t-1 landed (store acks hidden under TAIL)
        cur ^= 1;
    }

    // ---------- epilogue ----------
    if (l == 20) sAcc[2] = qerr;
    if (l == 21) sAcc[3] = merr;
    wsync_lds();
    if (l == 0) {
        out[O_DV + b*2 + 0] = dv0;
        out[O_DV + b*2 + 1] = dv1;
        ws[b] = fmaxf(sAcc[2], sAcc[3]);
    }
    if (l < 12) out[O_VX + b*12 + l] = sVxe[l*16 + 12];
    #pragma unroll
    for (int idx = l; idx < 144; idx += 64)
        out[O_VXX + (size_t)b*144 + idx] = sVxe[(idx/12)*16 + (idx%12)];
}

__global__ __launch_bounds__(256) void opt_reduce(const float* __restrict__ ws,
                                                  float* __restrict__ out)
{
    float v = ws[threadIdx.x];
    #pragma unroll
    for (int o = 32; o > 0; o >>= 1) v = fmaxf(v, __shfl_down(v, o, 64));
    __shared__ float m[4];
    if ((threadIdx.x & 63) == 0) m[threadIdx.x >> 6] = v;
    __syncthreads();
    if (threadIdx.x == 0) out[O_OPT] = fmaxf(fmaxf(m[0], m[1]), fmaxf(m[2], m[3]));
}

extern "C" void kernel_launch(void* const* d_in, const int* in_sizes, int n_in,
                              void* d_out, int out_size, void* d_ws, size_t ws_size,
                              hipStream_t stream) {
    const float* qx  = (const float*)d_in[0];
    const float* qu  = (const float*)d_in[1];
    const float* qxx = (const float*)d_in[2];
    const float* qxu = (const float*)d_in[3];
    const float* quu = (const float*)d_in[4];
    const float* fx  = (const float*)d_in[5];
    const float* fu  = (const float*)d_in[6];
    const float* fxx = (const float*)d_in[7];
    const float* fxu = (const float*)d_in[8];
    const float* fuu = (const float*)d_in[9];
    const float* cx  = (const float*)d_in[10];
    const float* cu  = (const float*)d_in[11];
    const float* c_  = (const float*)d_in[12];
    const float* s_  = (const float*)d_in[13];
    const float* px  = (const float*)d_in[14];
    const float* pxx = (const float*)d_in[15];
    float* out = (float*)d_out;
    float* ws  = (float*)d_ws;

    hipLaunchKernelGGL(ddp_backward, dim3(B_), dim3(64), 0, stream,
                       qx, qu, qxx, qxu, quu, fx, fu, fxx, fxu, fuu,
                       cx, cu, c_, s_, px, pxx, out, ws);
    hipLaunchKernelGGL(opt_reduce, dim3(1), dim3(256), 0, stream, ws, out);
}

// Round 5
// 691.212 us; speedup vs baseline: 1.0556x; 1.0556x over previous
//
#include <hip/hip_runtime.h>
#include <cstdint>
#include <cstddef>

#define B_  256
#define T_  128
#define NS_ 12
#define NC_ 4
#define M_  6

constexpr float MU_F      = 0.1f;
constexpr float REG_FAC_F = (float)(1.6 * 1.6 - 1.0);   // 1.56 -> f32

// ---- staging buffer layout (float offsets) ----
#define OF_FX   0
#define OF_FU   144
#define OF_FXX  192
#define OF_FXU  1920
#define OF_FUU  2496
#define OF_QXX  2688
#define OF_QXU  2832
#define OF_QUU  2880
#define OF_QX   2896
#define OF_QU   2908
#define OF_CX   2912
#define OF_CU   2984
#define OF_C    3008
#define OF_S    3014
#define STG_N   3020

// ---- output layout (float offsets into d_out) ----
#define O_KU    0
#define O_KUBIG 131072
#define O_KS    1703936
#define O_KSBIG 1900544
#define O_DV    4259840
#define O_OPT   4260352
#define O_VX    4260353
#define O_VXX   4263425

__device__ __forceinline__ void wsync_lds() {
    asm volatile("s_waitcnt lgkmcnt(0)" ::: "memory");
}
__device__ __forceinline__ void wsync_all() {
    asm volatile("s_waitcnt vmcnt(0) lgkmcnt(0)" ::: "memory");
}

__device__ __forceinline__ void gl_lds16(const float* g, float* l) {
    __builtin_amdgcn_global_load_lds((const __attribute__((address_space(1))) void*)g,
                                     (__attribute__((address_space(3))) void*)l, 16, 0, 0);
}
__device__ __forceinline__ void gl_lds4(const float* g, float* l) {
    __builtin_amdgcn_global_load_lds((const __attribute__((address_space(1))) void*)g,
                                     (__attribute__((address_space(3))) void*)l, 4, 0, 0);
}
__device__ __forceinline__ float4 ld4(const float* p)  { return *reinterpret_cast<const float4*>(p); }
__device__ __forceinline__ void   st4(float* p, float4 v) { *reinterpret_cast<float4*>(p) = v; }

// 2 waves per block: wave 0 = compute chain (no VMEM in-loop), wave 1 = service
// (prefetch DMA, all global stores, dV/err). Sync = 2 s_barriers per step.
__global__ __launch_bounds__(128) void ddp_backward(
    const float* __restrict__ qx,  const float* __restrict__ qu,
    const float* __restrict__ qxx, const float* __restrict__ qxu,
    const float* __restrict__ quu, const float* __restrict__ fx,
    const float* __restrict__ fu,  const float* __restrict__ fxx,
    const float* __restrict__ fxu, const float* __restrict__ fuu,
    const float* __restrict__ cx,  const float* __restrict__ cu,
    const float* __restrict__ c_,  const float* __restrict__ s_,
    const float* __restrict__ px,  const float* __restrict__ pxx,
    float* __restrict__ out, float* __restrict__ ws)
{
    const int tid = threadIdx.x;
    const int l   = tid & 63;
    const int wv  = tid >> 6;     // 0 = compute wave, 1 = service wave
    const int b   = blockIdx.x;

    __shared__ alignas(16) float stg[2][STG_N];
    __shared__ alignas(16) float sVxe[192];     // carry [12][16]: cols 0-11 Vxx, col 12 Vx
    __shared__ alignas(16) float sG[192];       // [p][k] stride 12: rows 0-11 fxV, 12-15 fuV
    __shared__ alignas(16) float sOUT[192];     // [i][q] stride 16: q<12 Qxx2, q>=12 tempQux[a][i]
    __shared__ alignas(16) float sQuu2[16], sM4[16];
    __shared__ alignas(16) float sQP[16];       // Qx2 (0-11) | Qu final (12-15)
    __shared__ alignas(16) float sKu[48];       // [a][i] stride 12
    __shared__ alignas(16) float sku[4];
    __shared__ alignas(16) float sR[8], sCINV[8], sSC[8];
    __shared__ float sAcc[4];

    const float* srcs[14] = {qx, qu, qxx, qxu, quu, fx, fu, fxx, fxu, fuu, cx, cu, c_, s_};

    // ---- per-lane role constants ----
    const int p   = l & 15, cq = l >> 4;
    const bool cq3 = (cq == 3);
    const int u1_x  = (p < 12) ? (OF_FX + p) : (OF_FU + p - 12);
    const int u1_xs = (p < 12) ? 12 : 4;
    const int u1_q0 = (p < 12) ? (OF_QX + p) : (OF_QU + p - 12);
    const int u1_w  = (p < 12) ? (OF_CX + p) : (OF_CU + p - 12);
    const int u1_ws = (p < 12) ? 12 : 4;
    const int pr = l >> 2, q4 = l & 3;
    const bool q43 = (q4 == 3);
    const int u2_q0 = (pr < 12) ? (q43 ? (OF_QXU + pr * 4) : (OF_QXX + pr * 12 + q4 * 4))
                                : (OF_QUU + (pr - 12) * 4);
    const int u2_x  = q43 ? OF_FU : (OF_FX + q4 * 4);
    const int u2_xs = q43 ? 4 : 12;
    const int u2_t  = (pr < 12) ? (q43 ? (OF_FXU + pr * 4) : (OF_FXX + pr * 12 + q4 * 4))
                                : (OF_FUU + (pr - 12) * 4);
    const int u2_ts = (pr < 12) ? (q43 ? 48 : 144) : 16;
    const int u2_w  = q43 ? OF_CU : (OF_CX + q4 * 4);
    const int u2_ws = q43 ? 4 : 12;
    const int i5 = l / 3, jq5 = l % 3;

    auto prefetch = [&](float* dst, int tt) {
        const uint32_t bt2 = (uint32_t)b * T_ + (uint32_t)tt;
        constexpr int ch_arr[22]  = {5,6,7,7,7,7,7,7,7,8,8,8,9,2,3,4,0,1,10,11,12,13};
        constexpr int ch_goff[22] = {0,0,0,256,512,768,1024,1280,1536,0,256,512,0,0,0,0,0,0,0,0,0,0};
        constexpr int ch_loff[22] = {OF_FX, OF_FU,
                                     OF_FXX, OF_FXX+256, OF_FXX+512, OF_FXX+768,
                                     OF_FXX+1024, OF_FXX+1280, OF_FXX+1536,
                                     OF_FXU, OF_FXU+256, OF_FXU+512,
                                     OF_FUU, OF_QXX, OF_QXU, OF_QUU, OF_QX, OF_QU,
                                     OF_CX, OF_CU, OF_C, OF_S};
        constexpr int ch_nb[22]   = {576,192,1024,1024,1024,1024,1024,1024,768,
                                     1024,1024,256,768,576,192,64,48,16,288,96,24,24};
        constexpr int sl[14]      = {12,4,144,48,16,144,48,1728,576,192,72,24,6,6};
        #pragma unroll
        for (int ci = 0; ci < 22; ++ci) {
            const uint32_t off = bt2 * (uint32_t)sl[ch_arr[ci]] + (uint32_t)ch_goff[ci];
            const float* g = srcs[ch_arr[ci]] + (size_t)off;
            float* dl = dst + ch_loff[ci];
            if ((ch_nb[ci] & 15) == 0) {
                if (l * 16 < ch_nb[ci]) gl_lds16(g + l * 4, dl);
            } else {
                if (l * 4  < ch_nb[ci]) gl_lds4 (g + l,     dl);
            }
        }
    };

    // ---------- prologue ----------
    if (wv == 0) {
        #pragma unroll
        for (int idx = l; idx < 192; idx += 64) {
            const int r = idx >> 4, ci = idx & 15;
            float v = 0.f;
            if (ci < 12)       v = pxx[(size_t)b * 144 + r * 12 + ci];
            else if (ci == 12) v = px[(size_t)b * 12 + r];
            sVxe[idx] = v;
        }
        wsync_lds();
    } else {
        prefetch(stg[0], T_ - 1);
        wsync_all();
    }
    __builtin_amdgcn_s_barrier();

    float dv0 = 0.f, dv1 = 0.f, qerr = 0.f, merr = 0.f;
    int cur = 0;
    for (int t = T_ - 1; t >= 0; --t) {
        const float* S = stg[cur];
        const uint32_t bt = (uint32_t)b * T_ + (uint32_t)t;

        if (wv == 1) {
            // service wave: issue next-step prefetch; loads land during wave 0's compute
            if (t > 0) prefetch(stg[cur ^ 1], t - 1);
        } else {
            // ================= preloads =================
            float fcol[12];
            float4 vrow[12];
            #pragma unroll
            for (int m = 0; m < 12; ++m) fcol[m] = S[u1_x + m * u1_xs];
            #pragma unroll
            for (int m = 0; m < 12; ++m) vrow[m] = ld4(sVxe + m * 16 + cq * 4);
            const float4 csq0 = ld4(S + OF_C);
            const float4 csq1 = ld4(S + OF_C + 4);
            const float4 csq2 = ld4(S + OF_C + 8);
            float4 u2f[12];
            #pragma unroll
            for (int k = 0; k < 12; ++k) u2f[k] = ld4(S + u2_x + k * u2_xs);
            const float4 u2q0 = ld4(S + u2_q0);
            float4 u2tv[12];
            #pragma unroll
            for (int s2 = 0; s2 < 12; ++s2) u2tv[s2] = ld4(S + u2_t + s2 * u2_ts);

            // ================= U1: G = [fx|fu]^T [Vxx|Vx], Qx/Qu chain, r/cinv/sc =================
            {
                if (cq3 && p < 6) {
                    const float cc = S[OF_C + p], sv = S[OF_S + p];
                    sR[p]    = sv * cc + MU_F;
                    sCINV[p] = 1.0f / cc;
                    sSC[p]   = sv / cc;
                }
                float accx = 0.f, accy = 0.f, accz = 0.f, accw = 0.f;
                if (cq3) {
                    float a0 = S[u1_q0];
                    #pragma unroll
                    for (int k = 0; k < 6; ++k) a0 += S[u1_w + k * u1_ws] * S[OF_S + k];
                    accx = a0;
                }
                #pragma unroll
                for (int m = 0; m < 12; ++m) {
                    const float f = fcol[m];
                    accx += f * vrow[m].x; accy += f * vrow[m].y;
                    accz += f * vrow[m].z; accw += f * vrow[m].w;
                }
                if (!cq3) {
                    st4(sG + p * 12 + cq * 4, make_float4(accx, accy, accz, accw));
                } else {
                    // redundant per-lane IEEE cinv/r (bitwise == sCINV/sR above)
                    const float cv6[6] = {csq0.x, csq0.y, csq0.z, csq0.w, csq1.x, csq1.y};
                    const float sv6[6] = {csq1.z, csq1.w, csq2.x, csq2.y, csq2.z, csq2.w};
                    float rck[6], rrk[6];
                    #pragma unroll
                    for (int k = 0; k < 6; ++k) { rck[k] = 1.0f / cv6[k]; rrk[k] = sv6[k] * cv6[k] + MU_F; }
                    #pragma unroll
                    for (int k = 0; k < 6; ++k) accx -= S[u1_w + k * u1_ws] * rck[k] * rrk[k];
                    sQP[p] = accx;
                }
            }
            wsync_lds();   // F1

            // ================= U2: {Qxx2 | tempQux | QuuR} + fenceless B2 =================
            {
                float vx[12];
                #pragma unroll
                for (int m = 0; m < 12; ++m) vx[m] = sVxe[m * 16 + 12];
                float rsc[6];
                #pragma unroll
                for (int k = 0; k < 6; ++k) rsc[k] = sSC[k];

                const float4 g0 = ld4(sG + pr * 12);
                const float4 g1 = ld4(sG + pr * 12 + 4);
                const float4 g2 = ld4(sG + pr * 12 + 8);
                const float gk[12] = {g0.x,g0.y,g0.z,g0.w, g1.x,g1.y,g1.z,g1.w, g2.x,g2.y,g2.z,g2.w};

                float4 acc = u2q0;
                #pragma unroll
                for (int k = 0; k < 12; ++k) {
                    const float4 f = u2f[k];
                    acc.x += gk[k]*f.x; acc.y += gk[k]*f.y; acc.z += gk[k]*f.z; acc.w += gk[k]*f.w;
                }
                #pragma unroll
                for (int s2 = 0; s2 < 12; ++s2) {
                    const float4 tv = u2tv[s2];
                    acc.x += vx[s2]*tv.x; acc.y += vx[s2]*tv.y; acc.z += vx[s2]*tv.z; acc.w += vx[s2]*tv.w;
                }
                if (pr < 12) {
                    #pragma unroll
                    for (int k = 0; k < 6; ++k) {
                        const float t2 = rsc[k] * S[OF_CX + k * 12 + pr];
                        const float4 cv = ld4(S + u2_w + k * u2_ws);
                        acc.x -= t2*cv.x; acc.y -= t2*cv.y; acc.z -= t2*cv.z; acc.w -= t2*cv.w;
                    }
                    st4(sOUT + pr * 16 + q4 * 4, acc);
                } else if (q43) {
                    // B2 without transpose fence: recompute QuuR[bb][a] fresh from sG
                    // (bitwise == lane-bb's acc component a: same init, same k/s2 order)
                    const int a = pr - 12;
                    const float accq[4] = {acc.x, acc.y, acc.z, acc.w};   // QuuR[a][bb]
                    float q2v[4];
                    #pragma unroll
                    for (int bb = 0; bb < 4; ++bb) {
                        float cacc = S[OF_QUU + bb*4 + a];
                        #pragma unroll
                        for (int k = 0; k < 12; ++k)
                            cacc += sG[(12 + bb) * 12 + k] * S[OF_FU + k*4 + a];
                        #pragma unroll
                        for (int s2 = 0; s2 < 12; ++s2)
                            cacc += vx[s2] * S[OF_FUU + s2*16 + bb*4 + a];
                        const float q = 0.5f * (accq[bb] + cacc);
                        float cs2 = 0.f;
                        #pragma unroll
                        for (int k = 0; k < 6; ++k)
                            cs2 += rsc[k] * S[OF_CU + k*4 + a] * S[OF_CU + k*4 + bb];
                        q2v[bb] = q - cs2;
                    }
                    const float4 quuq = ld4(S + OF_QUU + a * 4);
                    st4(sQuu2 + a * 4, make_float4(q2v[0], q2v[1], q2v[2], q2v[3]));
                    st4(sM4   + a * 4, make_float4(q2v[0] + quuq.x * REG_FAC_F,
                                                   q2v[1] + quuq.y * REG_FAC_F,
                                                   q2v[2] + quuq.z * REG_FAC_F,
                                                   q2v[3] + quuq.w * REG_FAC_F));
                }
            }
            wsync_lds();   // F2

            // ================= LU: 4x4 solve (13 RHS), results -> LDS only =================
            if (l < 13) {
                float a00=sM4[0],  a01=sM4[1],  a02=sM4[2],  a03=sM4[3];
                float a10=sM4[4],  a11=sM4[5],  a12=sM4[6],  a13=sM4[7];
                float a20=sM4[8],  a21=sM4[9],  a22=sM4[10], a23=sM4[11];
                float a30=sM4[12], a31=sM4[13], a32=sM4[14], a33=sM4[15];
                const float i0 = 1.0f / a00;
                const float l10 = a10*i0, l20 = a20*i0, l30 = a30*i0;
                a11 -= l10*a01; a12 -= l10*a02; a13 -= l10*a03;
                a21 -= l20*a01; a22 -= l20*a02; a23 -= l20*a03;
                a31 -= l30*a01; a32 -= l30*a02; a33 -= l30*a03;
                const float i1 = 1.0f / a11;
                const float l21 = a21*i1, l31 = a31*i1;
                a22 -= l21*a12; a23 -= l21*a13;
                a32 -= l31*a12; a33 -= l31*a13;
                const float i2 = 1.0f / a22;
                const float l32 = a32*i2;
                a33 -= l32*a23;

                float r0, r1, r2, r3;
                if (l == 0) { const float4 q = ld4(sQP + 12);             r0=q.x; r1=q.y; r2=q.z; r3=q.w; }
                else        { const float4 q = ld4(sOUT + (l-1)*16 + 12); r0=q.x; r1=q.y; r2=q.z; r3=q.w; }

                const float y0 = r0;
                const float y1 = r1 - l10*y0;
                const float y2 = r2 - l20*y0 - l21*y1;
                const float y3 = r3 - l30*y0 - l31*y1 - l32*y2;
                float x3 = y3 / a33;
                float x2 = (y2 - a23*x3) * i2;
                float x1 = (y1 - a12*x2 - a13*x3) * i1;
                float x0 = (y0 - a01*x1 - a02*x2 - a03*x3) * i0;
                x0 = -x0; x1 = -x1; x2 = -x2; x3 = -x3;

                if (l == 0) { sku[0]=x0; sku[1]=x1; sku[2]=x2; sku[3]=x3; }
                else {
                    const int i = l - 1;
                    sKu[i]=x0; sKu[12+i]=x1; sKu[24+i]=x2; sKu[36+i]=x3;
                }
            }
            wsync_lds();   // F3: sku/sKu visible
        }
        __builtin_amdgcn_s_barrier();   // bar1: releases service wave

        if (wv == 0) {
            // ================= TAIL: Vxx | Vx =================
            if (l < 36) {
                const int i = i5, jq = jq5;
                const float4 v14  = ld4(sOUT + i*16 + jq*4);
                const float4 tqi4 = ld4(sOUT + i*16 + 12);
                const float tqi[4] = {tqi4.x, tqi4.y, tqi4.z, tqi4.w};
                float kuj[4][4], kui[4];
                #pragma unroll
                for (int a = 0; a < 4; ++a) {
                    const float4 kv = ld4(sKu + a*12 + jq*4);
                    kuj[a][0]=kv.x; kuj[a][1]=kv.y; kuj[a][2]=kv.z; kuj[a][3]=kv.w;
                    kui[a] = sKu[a*12 + i];
                }
                float4 q2r[4];
                #pragma unroll
                for (int bb = 0; bb < 4; ++bb) q2r[bb] = ld4(sQuu2 + bb*4);
                float kqi[4] = {0.f, 0.f, 0.f, 0.f};
                #pragma unroll
                for (int bb = 0; bb < 4; ++bb) {
                    kqi[0] += kui[bb]*q2r[bb].x; kqi[1] += kui[bb]*q2r[bb].y;
                    kqi[2] += kui[bb]*q2r[bb].z; kqi[3] += kui[bb]*q2r[bb].w;
                }
                float kqj[4][4];
                #pragma unroll
                for (int r = 0; r < 4; ++r) { kqj[r][0]=0.f; kqj[r][1]=0.f; kqj[r][2]=0.f; kqj[r][3]=0.f; }
                #pragma unroll
                for (int bb = 0; bb < 4; ++bb) {
                    #pragma unroll
                    for (int r = 0; r < 4; ++r) {
                        kqj[r][0] += kuj[bb][r]*q2r[bb].x; kqj[r][1] += kuj[bb][r]*q2r[bb].y;
                        kqj[r][2] += kuj[bb][r]*q2r[bb].z; kqj[r][3] += kuj[bb][r]*q2r[bb].w;
                    }
                }
                const float v1a[4] = {v14.x, v14.y, v14.z, v14.w};
                float v2[4], tqj[4][4];
                #pragma unroll
                for (int r = 0; r < 4; ++r) {
                    const int j = jq*4 + r;
                    v2[r] = sOUT[j*16 + i];
                    const float4 tq = ld4(sOUT + j*16 + 12);
                    tqj[r][0]=tq.x; tqj[r][1]=tq.y; tqj[r][2]=tq.z; tqj[r][3]=tq.w;
                }
                float res[4];
                #pragma unroll
                for (int r = 0; r < 4; ++r) {
                    float qk = 0.f, kk1 = 0.f, kk2 = 0.f;
                    #pragma unroll
                    for (int a = 0; a < 4; ++a) {
                        qk  += tqi[a]*kuj[a][r] + tqj[r][a]*kui[a];
                        kk1 += kqi[a]*kuj[a][r];
                        kk2 += kqj[r][a]*kui[a];
                    }
                    res[r] = 0.5f*(v1a[r] + v2[r]) + qk + 0.5f*(kk1 + kk2);
                }
                st4(sVxe + i*16 + jq*4, make_float4(res[0], res[1], res[2], res[3]));
            } else if (l < 48) {
                const int i = l - 36;
                float kub[4];
                #pragma unroll
                for (int bb = 0; bb < 4; ++bb) kub[bb] = sKu[bb*12 + i];
                float4 q2r[4];
                #pragma unroll
                for (int bb = 0; bb < 4; ++bb) q2r[bb] = ld4(sQuu2 + bb*4);
                float ktq[4] = {0.f, 0.f, 0.f, 0.f};
                #pragma unroll
                for (int bb = 0; bb < 4; ++bb) {
                    ktq[0] += kub[bb]*q2r[bb].x; ktq[1] += kub[bb]*q2r[bb].y;
                    ktq[2] += kub[bb]*q2r[bb].z; ktq[3] += kub[bb]*q2r[bb].w;
                }
                float acc = sQP[i];
                #pragma unroll
                for (int a = 0; a < 4; ++a)
                    acc += kub[a]*sQP[12+a] + ktq[a]*sku[a] + sOUT[i*16+12+a]*sku[a];
                st4(sVxe + i*16 + 12, make_float4(acc, 0.f, 0.f, 0.f));
            }
            wsync_lds();
        } else {
            // ================= service: global stores + dV/err =================
            if (l == 40) {
                st4(out + O_KU + (size_t)bt * 4, ld4(sku));
            } else if (l > 40 && l <= 52) {
                const int i = l - 41;
                float* Kg = out + O_KUBIG + (size_t)bt * 48;
                Kg[i]    = sKu[i];
                Kg[12+i] = sKu[12+i];
                Kg[24+i] = sKu[24+i];
                Kg[36+i] = sKu[36+i];
            }
            if (l < 18) {
                const int k = i5, iq = jq5;
                const float4 cxv = ld4(S + OF_CX + k*12 + iq*4);
                float a0 = cxv.x, a1 = cxv.y, a2 = cxv.z, a3v = cxv.w;
                #pragma unroll
                for (int a = 0; a < 4; ++a) {
                    const float  cua = S[OF_CU + k*4 + a];
                    const float4 kv  = ld4(sKu + a*12 + iq*4);
                    a0 += cua*kv.x; a1 += cua*kv.y; a2 += cua*kv.z; a3v += cua*kv.w;
                }
                const float ns = -sSC[k];
                st4(out + O_KSBIG + (size_t)bt * 72 + k*12 + iq*4,
                    make_float4(ns*a0, ns*a1, ns*a2, ns*a3v));
                if (iq == 0) {
                    float cuku = 0.f;
                    #pragma unroll
                    for (int a = 0; a < 4; ++a) cuku += S[OF_CU + k*4 + a] * sku[a];
                    out[O_KS + (size_t)bt * 6 + k] = -sCINV[k] * (sR[k] + S[OF_S + k] * cuku);
                }
            } else if (l == 32) {
                float d0 = 0.f;
                #pragma unroll
                for (int a = 0; a < 4; ++a) d0 += sku[a] * sQP[12 + a];
                dv0 += d0;
                float d1 = 0.f;
                #pragma unroll
                for (int a = 0; a < 4; ++a)
                    #pragma unroll
                    for (int b2 = 0; b2 < 4; ++b2) d1 += sku[a] * sQuu2[a*4 + b2] * sku[b2];
                dv1 += 0.5f * d1;
            } else if (l == 33) {
                float m = 0.f;
                #pragma unroll
                for (int a = 0; a < 4; ++a) m = fmaxf(m, fabsf(sQP[12 + a]));
                qerr = fmaxf(qerr, m);
            } else if (l == 34) {
                float m = 0.f;
                #pragma unroll
                for (int k = 0; k < 6; ++k) m = fmaxf(m, fabsf(sR[k]));
                merr = fmaxf(merr, m);
            }
            wsync_all();   // prefetch landed (store acks overlap wave 0's TAIL)
        }
        __builtin_amdgcn_s_barrier();   // bar2: next-step staging + carry ready
        cur ^= 1;
    }

    // ---------- epilogue ----------
    if (wv == 0) {
        if (l < 12) out[O_VX + b*12 + l] = sVxe[l*16 + 12];
        #pragma unroll
        for (int idx = l; idx < 144; idx += 64)
            out[O_VXX + (size_t)b*144 + idx] = sVxe[(idx/12)*16 + (idx%12)];
    } else {
        if (l == 33) sAcc[2] = qerr;
        if (l == 34) sAcc[3] = merr;
        wsync_lds();
        if (l == 32) {
            out[O_DV + b*2 + 0] = dv0;
            out[O_DV + b*2 + 1] = dv1;
        }
        if (l == 33) ws[b] = fmaxf(sAcc[2], sAcc[3]);
    }
}

__global__ __launch_bounds__(256) void opt_reduce(const float* __restrict__ ws,
                                                  float* __restrict__ out)
{
    float v = ws[threadIdx.x];
    #pragma unroll
    for (int o = 32; o > 0; o >>= 1) v = fmaxf(v, __shfl_down(v, o, 64));
    __shared__ float m[4];
    if ((threadIdx.x & 63) == 0) m[threadIdx.x >> 6] = v;
    __syncthreads();
    if (threadIdx.x == 0) out[O_OPT] = fmaxf(fmaxf(m[0], m[1]), fmaxf(m[2], m[3]));
}

extern "C" void kernel_launch(void* const* d_in, const int* in_sizes, int n_in,
                              void* d_out, int out_size, void* d_ws, size_t ws_size,
                              hipStream_t stream) {
    const float* qx  = (const float*)d_in[0];
    const float* qu  = (const float*)d_in[1];
    const float* qxx = (const float*)d_in[2];
    const float* qxu = (const float*)d_in[3];
    const float* quu = (const float*)d_in[4];
    const float* fx  = (const float*)d_in[5];
    const float* fu  = (const float*)d_in[6];
    const float* fxx = (const float*)d_in[7];
    const float* fxu = (const float*)d_in[8];
    const float* fuu = (const float*)d_in[9];
    const float* cx  = (const float*)d_in[10];
    const float* cu  = (const float*)d_in[11];
    const float* c_  = (const float*)d_in[12];
    const float* s_  = (const float*)d_in[13];
    const float* px  = (const float*)d_in[14];
    const float* pxx = (const float*)d_in[15];
    float* out = (float*)d_out;
    float* ws  = (float*)d_ws;

    hipLaunchKernelGGL(ddp_backward, dim3(B_), dim3(128), 0, stream,
                       qx, qu, qxx, qxu, quu, fx, fu, fxx, fxu, fuu,
                       cx, cu, c_, s_, px, pxx, out, ws);
    hipLaunchKernelGGL(opt_reduce, dim3(1), dim3(256), 0, stream, ws, out);
}